// Round 7
// baseline (563.787 us; speedup 1.0000x reference)
//
#include <hip/hip_runtime.h>

// Problem constants (fixed by the reference setup_inputs).
#define VSZ 50000   // vocab
#define ESZ 100     // embedding dim
#define HSZ 64      // hidden
#define GSZ 256     // 4*H (gate width, PyTorch order i,f,g,o)
#define BSZ 256     // batch
#define TSZ 512     // seq len

__device__ __forceinline__ float fast_rcp(float x) { return __builtin_amdgcn_rcpf(x); }
__device__ __forceinline__ float sigmoid_f(float x) { return fast_rcp(1.f + __expf(-x)); }
__device__ __forceinline__ float tanh_f(float x) {
    float e = __expf(2.f * x);
    return 1.f - 2.f * fast_rcp(e + 1.f);
}

// ---------------------------------------------------------------------------
// Kernel A: G[v, col] = sum_e emb[v,e]*w_ih0[row,e] + b_ih0[row] + b_hh0[row],
// PERMUTED col = 4*(row%64) + row/64 so the recurrent kernel's lane (q,j)
// reads its gate scalar at col 4q+j.
// r5's s_load chain stalled ~4000cy/iter (SGPR staging serializes; 106us).
// New: stage 8 emb rows in LDS (coalesced float4), then every thread reads
// them as uniform-address ds_read_b128 BROADCASTS (conflict-free, 1/4 the
// issue count of r1's scalar ds_read_b32) against its register-resident
// w_ih0 row. ~200 b128 + 800 FMA per chunk per wave.
// ---------------------------------------------------------------------------
__global__ __launch_bounds__(256, 2) void build_table(
    const float* __restrict__ emb, const float* __restrict__ w_ih0,
    const float* __restrict__ b_ih0, const float* __restrict__ b_hh0,
    float* __restrict__ Gt)
{
    const int g = threadIdx.x;            // PyTorch gate-row index 0..255
    const int row0 = blockIdx.x * 64;
    const int col = ((g & 63) << 2) + (g >> 6);   // permuted column

    float w[ESZ];
    #pragma unroll
    for (int e = 0; e < ESZ; e += 4) {
        float4 v = *(const float4*)(w_ih0 + g * ESZ + e);
        w[e] = v.x; w[e + 1] = v.y; w[e + 2] = v.z; w[e + 3] = v.w;
    }
    const float bias = b_ih0[g] + b_hh0[g];

    __shared__ __align__(16) float rows[8 * ESZ];
    float4* const buf4 = (float4*)rows;
    const bool full = (row0 + 64 <= VSZ);         // 781 full blocks + 1 tail

    #pragma unroll 1
    for (int c = 0; c < 8; ++c) {
        const int rbase = row0 + c * 8;
        if (full) {
            const float4* src = (const float4*)(emb + (size_t)rbase * ESZ);
            if (g < 200) buf4[g] = src[g];        // 200 float4 = 8 rows
        } else {
            for (int i = g; i < 8 * ESZ; i += 256) {
                const int idx = rbase * ESZ + i;
                rows[i] = (idx < VSZ * ESZ) ? emb[idx] : 0.f;
            }
        }
        __syncthreads();
        #pragma unroll 1
        for (int r = 0; r < 8; ++r) {
            const int rr = rbase + r;
            const float4* hv = (const float4*)(rows + r * ESZ);
            float a0 = bias, a1 = 0.f, a2 = 0.f, a3 = 0.f;
            #pragma unroll
            for (int e = 0; e < 25; ++e) {
                float4 u = hv[e];                 // uniform addr -> broadcast
                a0 += u.x * w[4 * e];     a1 += u.y * w[4 * e + 1];
                a2 += u.z * w[4 * e + 2]; a3 += u.w * w[4 * e + 3];
            }
            if (rr < VSZ) Gt[(size_t)rr * GSZ + col] = (a0 + a1) + (a2 + a3);
        }
        __syncthreads();                          // reads done before restage
    }
}

// ---------------------------------------------------------------------------
// Kernel B: fused 2-layer LSTM + FC head, 1 block (768 thr) per batch row.
//
// ONLY change vs r5: __attribute__((amdgpu_waves_per_eu(2,3))).
// r4/r5 post-mortem: launch_bounds' 2nd arg sets only the MIN waves/EU (a
// VGPR *upper* bound); the allocator's occupancy TARGET stayed at its
// default high value, so it spilled the 64 pinned weight floats to scratch
// (VGPR_Count=52) and re-loaded them every step -- timing identical to the
// global-reload bug. waves_per_eu(2,3) caps the occupancy target at 3
// waves/EU (= exactly our 12-wave block), giving regalloc a ~170-VGPR
// budget and no incentive to spill.
//
// Group A (tid<256): layer 0. unit q = tid>>2, slice j = tid&3 (16 h-vals).
// Group B (tid>=256): layer 1. lt=tid-256, q=lt>>3, j=lt&7 (8 h-vals), with
//   the H operand = h0-slice ++ h1-slice so the dot code is identical to A's.
// 64 weight floats/thread, loaded ONCE and pinned with one-time volatile asm.
// Per step: 64 FMA -> reduce-scatter -> ONE activation per lane ->
// 3-shuffle allgather -> replicated c,h update, lane j==0 publishes h.
// A computes layer-0 step k while B computes layer-1 step k-1; ONE lgkm-only
// barrier per step (Gt prefetch stays in flight across it).
// ---------------------------------------------------------------------------
__device__ __forceinline__ void sync_lds() {
    asm volatile("s_waitcnt lgkmcnt(0)\n\ts_barrier" ::: "memory");
}

#define LD4(ptr, off) (*(const float4*)((ptr) + (off)))
#define PIN4(v) asm volatile("" : "+v"(v.x), "+v"(v.y), "+v"(v.z), "+v"(v.w))
#define DOT4(acc, Sa, Sb, Sc, Sd)                                  \
    acc += Sa.x*H0.x; acc += Sa.y*H0.y; acc += Sa.z*H0.z; acc += Sa.w*H0.w; \
    acc += Sb.x*H1.x; acc += Sb.y*H1.y; acc += Sb.z*H1.z; acc += Sb.w*H1.w; \
    acc += Sc.x*H2.x; acc += Sc.y*H2.y; acc += Sc.z*H2.z; acc += Sc.w*H2.w; \
    acc += Sd.x*H3.x; acc += Sd.y*H3.y; acc += Sd.z*H3.z; acc += Sd.w*H3.w

__global__ __launch_bounds__(768)
__attribute__((amdgpu_waves_per_eu(2, 3)))
void lstm_fused(
    const int* __restrict__ x, const float* __restrict__ Gt,
    const float* __restrict__ w_hh0,
    const float* __restrict__ w_ih1, const float* __restrict__ w_hh1,
    const float* __restrict__ b_ih1, const float* __restrict__ b_hh1,
    const float* __restrict__ fc_w, const float* __restrict__ fc_b,
    float* __restrict__ out)
{
    const int tid = threadIdx.x;
    const int b   = blockIdx.x;
    const bool isA = tid < 256;
    const int lt  = isA ? tid : (tid - 256);
    const int q   = isA ? (lt >> 2) : (lt >> 3);
    const int j   = isA ? (lt & 3) : (lt & 7);
    const int gt  = j & 3;                 // gate this lane owns post-reduce

    __shared__ __align__(16) float h0b[2][HSZ];
    __shared__ __align__(16) float h1b[2][HSZ];
    __shared__ int xtok[TSZ];

    // Weight slice pointers (row of gate g = g*64+q -> +g*4096 elements).
    const float* pw1 = isA ? (w_hh0 + q * HSZ + 16 * j)
                           : (w_ih1 + q * HSZ + 8 * j);
    const float* pw2 = isA ? (w_hh0 + q * HSZ + 16 * j + 8)
                           : (w_hh1 + q * HSZ + 8 * j);

    float4 S00=LD4(pw1,0),     S01=LD4(pw1,4),     S02=LD4(pw2,0),     S03=LD4(pw2,4);
    float4 S10=LD4(pw1,4096),  S11=LD4(pw1,4100),  S12=LD4(pw2,4096),  S13=LD4(pw2,4100);
    float4 S20=LD4(pw1,8192),  S21=LD4(pw1,8196),  S22=LD4(pw2,8192),  S23=LD4(pw2,8196);
    float4 S30=LD4(pw1,12288), S31=LD4(pw1,12292), S32=LD4(pw2,12288), S33=LD4(pw2,12292);
    // One-time volatile register pins: cannot be sunk/cloned/rematerialized.
    PIN4(S00); PIN4(S01); PIN4(S02); PIN4(S03);
    PIN4(S10); PIN4(S11); PIN4(S12); PIN4(S13);
    PIN4(S20); PIN4(S21); PIN4(S22); PIN4(S23);
    PIN4(S30); PIN4(S31); PIN4(S32); PIN4(S33);

    float addend_b = 0.f;                  // B: bias of its gate (invariant)
    if (!isA) addend_b = b_ih1[gt * HSZ + q] + b_hh1[gt * HSZ + q];
    const float mco = (gt == 2) ?  2.f : -1.f;   // unified activation consts
    const float Aco = (gt == 2) ?  1.f :  0.f;
    const float Bco = (gt == 2) ? -2.f :  1.f;

    if (tid < 128)      ((float*)h0b)[tid] = 0.f;        // both buffers
    else if (tid < 256) ((float*)h1b)[tid - 128] = 0.f;
    if (tid < TSZ) xtok[tid] = x[b * TSZ + tid];
    __syncthreads();

    float c = 0.f;
    float xg_cur = 0.f;
    if (isA) xg_cur = Gt[(size_t)xtok[0] * GSZ + 4 * q + j];

    #pragma unroll 1
    for (int k = 0; k <= TSZ; ++k) {
        // A: prefetch next token's gate scalar (survives the lgkm barrier).
        float xg_nxt = 0.f;
        if (isA && k + 1 < TSZ)
            xg_nxt = Gt[(size_t)xtok[k + 1] * GSZ + 4 * q + j];

        const float4* h0v = (const float4*)h0b[(k ^ 1) & 1];  // h0(k-1)
        const float4* h1v = (const float4*)h1b[k & 1];        // h1(k-2)
        const float4* hA  = h0v + (isA ? 4 * j : 2 * j);
        const float4* hB  = isA ? (h0v + 4 * j + 2) : (h1v + 2 * j);
        float4 H0 = hA[0], H1 = hA[1], H2 = hB[0], H3 = hB[1];

        float d0 = 0.f, d1 = 0.f, d2 = 0.f, d3 = 0.f;
        DOT4(d0, S00, S01, S02, S03);
        DOT4(d1, S10, S11, S12, S13);
        DOT4(d2, S20, S21, S22, S23);
        DOT4(d3, S30, S31, S32, S33);

        if (!isA) {                        // fold the two octet halves
            d0 += __shfl_xor(d0, 4, 64); d1 += __shfl_xor(d1, 4, 64);
            d2 += __shfl_xor(d2, 4, 64); d3 += __shfl_xor(d3, 4, 64);
        }
        // Reduce-scatter within quad: lane j&3 ends with gate j&3's dot.
        const bool lo2 = (j & 2) == 0;
        float u  = lo2 ? d2 : d0, v = lo2 ? d3 : d1;
        float ru = __shfl_xor(u, 2, 64), rv = __shfl_xor(v, 2, 64);
        float aa = (lo2 ? d0 : d2) + ru;
        float bb = (lo2 ? d1 : d3) + rv;
        const bool lo1 = (j & 1) == 0;
        float ws = lo1 ? bb : aa;
        float rw = __shfl_xor(ws, 1, 64);
        float s  = (lo1 ? aa : bb) + rw;

        s += isA ? xg_cur : addend_b;
        // One activation per lane: sigmoid (i,f,o) or tanh (g).
        float e   = __expf(mco * s);
        float act = fmaf(Bco, fast_rcp(1.f + e), Aco);

        // Allgather the 4 acts back across the quad (3 shuffles).
        float o1 = __shfl_xor(act, 1, 64);
        float ge = lo1 ? act : o1;         // even gate of this pair (i or g)
        float go = lo1 ? o1 : act;         // odd  gate (f or o)
        float pe = __shfl_xor(ge, 2, 64), po = __shfl_xor(go, 2, 64);
        float iact = lo2 ? ge : pe;
        float fact = lo2 ? go : po;
        float gact = lo2 ? pe : ge;
        float oact = lo2 ? po : go;

        const bool active = isA ? (k < TSZ) : (k >= 1);
        if (active) {
            c = fact * c + iact * gact;
            float hn = oact * tanh_f(c);
            if (j == 0) {
                if (isA) h0b[k & 1][q] = hn;              // h0(k)
                else     h1b[(k ^ 1) & 1][q] = hn;        // h1(k-1)
            }
        }
        xg_cur = xg_nxt;
        sync_lds();                        // lgkm-only: vmem stays in flight
    }

    // FC head on h1(T-1) = h1b[1] (wave 0 only).
    if (tid < HSZ) {
        float v = fmaxf(h1b[1][tid], 0.f) * fc_w[tid];
        #pragma unroll
        for (int off = 32; off > 0; off >>= 1) v += __shfl_down(v, off, 64);
        if (tid == 0) out[b] = sigmoid_f(v + fc_b[0]);
    }
}

extern "C" void kernel_launch(void* const* d_in, const int* in_sizes, int n_in,
                              void* d_out, int out_size, void* d_ws, size_t ws_size,
                              hipStream_t stream) {
    const int*   x     = (const int*)  d_in[0];
    const float* emb   = (const float*)d_in[1];
    const float* w_ih0 = (const float*)d_in[2];
    const float* w_hh0 = (const float*)d_in[3];
    const float* b_ih0 = (const float*)d_in[4];
    const float* b_hh0 = (const float*)d_in[5];
    const float* w_ih1 = (const float*)d_in[6];
    const float* w_hh1 = (const float*)d_in[7];
    const float* b_ih1 = (const float*)d_in[8];
    const float* b_hh1 = (const float*)d_in[9];
    const float* fc_w  = (const float*)d_in[10];
    const float* fc_b  = (const float*)d_in[11];
    float* out = (float*)d_out;

    // Workspace: permuted G table [V, 4H] fp32 = 51.2 MB.
    float* Gt = (float*)d_ws;

    build_table<<<dim3((VSZ + 63) / 64), dim3(256), 0, stream>>>(
        emb, w_ih0, b_ih0, b_hh0, Gt);
    lstm_fused<<<dim3(BSZ), dim3(768), 0, stream>>>(
        x, Gt, w_hh0, w_ih1, w_hh1, b_ih1, b_hh1, fc_w, fc_b, out);
}

// Round 8
// 537.246 us; speedup vs baseline: 1.0494x; 1.0494x over previous
//
#include <hip/hip_runtime.h>

// Problem constants (fixed by the reference setup_inputs).
#define VSZ 50000   // vocab
#define ESZ 100     // embedding dim
#define HSZ 64      // hidden
#define GSZ 256     // 4*H (gate width, PyTorch order i,f,g,o)
#define BSZ 256     // batch
#define TSZ 512     // seq len

__device__ __forceinline__ float fast_rcp(float x) { return __builtin_amdgcn_rcpf(x); }
__device__ __forceinline__ float sigmoid_f(float x) { return fast_rcp(1.f + __expf(-x)); }
__device__ __forceinline__ float tanh_f(float x) {
    float e = __expf(2.f * x);
    return 1.f - 2.f * fast_rcp(e + 1.f);
}

// ---------------------------------------------------------------------------
// Kernel A: G[v, col] = sum_e emb[v,e]*w_ih0[row,e] + b_ih0[row] + b_hh0[row],
// PERMUTED col = 4*(row%64) + row/64 so the recurrent kernel's lane (q,j)
// reads its gate scalar at col 4q+j.
// r5's s_load form (measured ~100us) -- r7's LDS-broadcast variant REGRESSED
// to ~130us (uniform ds_read_b128 issue cost > s_load chain). Reverted.
// ---------------------------------------------------------------------------
__global__ __launch_bounds__(256) void build_table(
    const float* __restrict__ emb, const float* __restrict__ w_ih0,
    const float* __restrict__ b_ih0, const float* __restrict__ b_hh0,
    float* __restrict__ Gt)
{
    const int g = threadIdx.x;            // PyTorch gate-row index 0..255
    const int row0 = blockIdx.x * 32;
    const int col = ((g & 63) << 2) + (g >> 6);   // permuted column

    float w[ESZ];
    #pragma unroll
    for (int e = 0; e < ESZ; e += 4) {
        float4 v = *(const float4*)(w_ih0 + g * ESZ + e);
        w[e] = v.x; w[e + 1] = v.y; w[e + 2] = v.z; w[e + 3] = v.w;
    }
    const float bias = b_ih0[g] + b_hh0[g];

    #pragma unroll 1
    for (int r = row0; r < row0 + 32 && r < VSZ; r += 4) {
        // VSZ % 4 == 0 and tiles are 32-aligned: quads never straddle the end.
        const int off0 = __builtin_amdgcn_readfirstlane(r * ESZ);
        const float* e0 = emb + off0;
        const float* e1 = e0 + ESZ;
        const float* e2 = e0 + 2 * ESZ;
        const float* e3 = e0 + 3 * ESZ;
        float a0 = bias, a1 = 0.f, a2 = 0.f, a3 = 0.f;
        float b0 = bias, b1 = 0.f, b2 = 0.f, b3 = 0.f;
        float c0 = bias, c1 = 0.f, c2 = 0.f, c3 = 0.f;
        float d0 = bias, d1 = 0.f, d2 = 0.f, d3 = 0.f;
        #pragma unroll
        for (int e = 0; e < ESZ; e += 4) {
            a0 += e0[e    ] * w[e    ]; a1 += e0[e + 1] * w[e + 1];
            a2 += e0[e + 2] * w[e + 2]; a3 += e0[e + 3] * w[e + 3];
            b0 += e1[e    ] * w[e    ]; b1 += e1[e + 1] * w[e + 1];
            b2 += e1[e + 2] * w[e + 2]; b3 += e1[e + 3] * w[e + 3];
            c0 += e2[e    ] * w[e    ]; c1 += e2[e + 1] * w[e + 1];
            c2 += e2[e + 2] * w[e + 2]; c3 += e2[e + 3] * w[e + 3];
            d0 += e3[e    ] * w[e    ]; d1 += e3[e + 1] * w[e + 1];
            d2 += e3[e + 2] * w[e + 2]; d3 += e3[e + 3] * w[e + 3];
        }
        Gt[(size_t)r       * GSZ + col] = (a0 + a1) + (a2 + a3);
        Gt[(size_t)(r + 1) * GSZ + col] = (b0 + b1) + (b2 + b3);
        Gt[(size_t)(r + 2) * GSZ + col] = (c0 + c1) + (c2 + c3);
        Gt[(size_t)(r + 3) * GSZ + col] = (d0 + d1) + (d2 + d3);
    }
}

// ---------------------------------------------------------------------------
// Kernel B: fused 2-layer LSTM + FC head, 1 block (768 thr) per batch row.
//
// ONLY change vs r7: the occupancy/register attributes.
// r4/r5/r7 post-mortem: VGPR_Count stuck at 52 = ceil(512/10) -- the backend
// holds its DEFAULT 10-waves/EU pressure target (launch_bounds' own attr
// emission apparently overrides/conflicts with a separate waves_per_eu), so
// regalloc spills the 64 pinned weight floats and reloads them every step
// with barrier-synchronized stalls. Fix attempt: drop __launch_bounds__
// entirely and set the register limit DIRECTLY:
//   amdgpu_flat_work_group_size(768,768)  exact WG size
//   amdgpu_waves_per_eu(2,3)              occupancy bound
//   amdgpu_num_vgpr(144)                  pressure limit itself (>=64+~45)
// 12 waves x 144 regs fits the file; runtime occupancy is 1 block/CU (grid
// 256 = CU count) regardless, so nothing is lost if the attr takes.
//
// Group A (tid<256): layer 0. unit q = tid>>2, slice j = tid&3 (16 h-vals).
// Group B (tid>=256): layer 1. lt=tid-256, q=lt>>3, j=lt&7 (8 h-vals), with
//   the H operand = h0-slice ++ h1-slice so the dot code is identical to A's.
// 64 weight floats/thread, loaded ONCE and pinned with one-time volatile asm.
// Per step: 64 FMA -> reduce-scatter -> ONE activation per lane ->
// 3-shuffle allgather -> replicated c,h update, lane j==0 publishes h.
// A computes layer-0 step k while B computes layer-1 step k-1; ONE lgkm-only
// barrier per step (Gt prefetch stays in flight across it).
// ---------------------------------------------------------------------------
__device__ __forceinline__ void sync_lds() {
    asm volatile("s_waitcnt lgkmcnt(0)\n\ts_barrier" ::: "memory");
}

#define LD4(ptr, off) (*(const float4*)((ptr) + (off)))
#define PIN4(v) asm volatile("" : "+v"(v.x), "+v"(v.y), "+v"(v.z), "+v"(v.w))
#define DOT4(acc, Sa, Sb, Sc, Sd)                                  \
    acc += Sa.x*H0.x; acc += Sa.y*H0.y; acc += Sa.z*H0.z; acc += Sa.w*H0.w; \
    acc += Sb.x*H1.x; acc += Sb.y*H1.y; acc += Sb.z*H1.z; acc += Sb.w*H1.w; \
    acc += Sc.x*H2.x; acc += Sc.y*H2.y; acc += Sc.z*H2.z; acc += Sc.w*H2.w; \
    acc += Sd.x*H3.x; acc += Sd.y*H3.y; acc += Sd.z*H3.z; acc += Sd.w*H3.w

__global__
__attribute__((amdgpu_flat_work_group_size(768, 768),
               amdgpu_waves_per_eu(2, 3),
               amdgpu_num_vgpr(144)))
void lstm_fused(
    const int* __restrict__ x, const float* __restrict__ Gt,
    const float* __restrict__ w_hh0,
    const float* __restrict__ w_ih1, const float* __restrict__ w_hh1,
    const float* __restrict__ b_ih1, const float* __restrict__ b_hh1,
    const float* __restrict__ fc_w, const float* __restrict__ fc_b,
    float* __restrict__ out)
{
    const int tid = threadIdx.x;
    const int b   = blockIdx.x;
    const bool isA = tid < 256;
    const int lt  = isA ? tid : (tid - 256);
    const int q   = isA ? (lt >> 2) : (lt >> 3);
    const int j   = isA ? (lt & 3) : (lt & 7);
    const int gt  = j & 3;                 // gate this lane owns post-reduce

    __shared__ __align__(16) float h0b[2][HSZ];
    __shared__ __align__(16) float h1b[2][HSZ];
    __shared__ int xtok[TSZ];

    // Weight slice pointers (row of gate g = g*64+q -> +g*4096 elements).
    const float* pw1 = isA ? (w_hh0 + q * HSZ + 16 * j)
                           : (w_ih1 + q * HSZ + 8 * j);
    const float* pw2 = isA ? (w_hh0 + q * HSZ + 16 * j + 8)
                           : (w_hh1 + q * HSZ + 8 * j);

    float4 S00=LD4(pw1,0),     S01=LD4(pw1,4),     S02=LD4(pw2,0),     S03=LD4(pw2,4);
    float4 S10=LD4(pw1,4096),  S11=LD4(pw1,4100),  S12=LD4(pw2,4096),  S13=LD4(pw2,4100);
    float4 S20=LD4(pw1,8192),  S21=LD4(pw1,8196),  S22=LD4(pw2,8192),  S23=LD4(pw2,8196);
    float4 S30=LD4(pw1,12288), S31=LD4(pw1,12292), S32=LD4(pw2,12288), S33=LD4(pw2,12292);
    // One-time volatile register pins: cannot be sunk/cloned/rematerialized.
    PIN4(S00); PIN4(S01); PIN4(S02); PIN4(S03);
    PIN4(S10); PIN4(S11); PIN4(S12); PIN4(S13);
    PIN4(S20); PIN4(S21); PIN4(S22); PIN4(S23);
    PIN4(S30); PIN4(S31); PIN4(S32); PIN4(S33);

    float addend_b = 0.f;                  // B: bias of its gate (invariant)
    if (!isA) addend_b = b_ih1[gt * HSZ + q] + b_hh1[gt * HSZ + q];
    const float mco = (gt == 2) ?  2.f : -1.f;   // unified activation consts
    const float Aco = (gt == 2) ?  1.f :  0.f;
    const float Bco = (gt == 2) ? -2.f :  1.f;

    if (tid < 128)      ((float*)h0b)[tid] = 0.f;        // both buffers
    else if (tid < 256) ((float*)h1b)[tid - 128] = 0.f;
    if (tid < TSZ) xtok[tid] = x[b * TSZ + tid];
    __syncthreads();

    float c = 0.f;
    float xg_cur = 0.f;
    if (isA) xg_cur = Gt[(size_t)xtok[0] * GSZ + 4 * q + j];

    #pragma unroll 1
    for (int k = 0; k <= TSZ; ++k) {
        // A: prefetch next token's gate scalar (survives the lgkm barrier).
        float xg_nxt = 0.f;
        if (isA && k + 1 < TSZ)
            xg_nxt = Gt[(size_t)xtok[k + 1] * GSZ + 4 * q + j];

        const float4* h0v = (const float4*)h0b[(k ^ 1) & 1];  // h0(k-1)
        const float4* h1v = (const float4*)h1b[k & 1];        // h1(k-2)
        const float4* hA  = h0v + (isA ? 4 * j : 2 * j);
        const float4* hB  = isA ? (h0v + 4 * j + 2) : (h1v + 2 * j);
        float4 H0 = hA[0], H1 = hA[1], H2 = hB[0], H3 = hB[1];

        float d0 = 0.f, d1 = 0.f, d2 = 0.f, d3 = 0.f;
        DOT4(d0, S00, S01, S02, S03);
        DOT4(d1, S10, S11, S12, S13);
        DOT4(d2, S20, S21, S22, S23);
        DOT4(d3, S30, S31, S32, S33);

        if (!isA) {                        // fold the two octet halves
            d0 += __shfl_xor(d0, 4, 64); d1 += __shfl_xor(d1, 4, 64);
            d2 += __shfl_xor(d2, 4, 64); d3 += __shfl_xor(d3, 4, 64);
        }
        // Reduce-scatter within quad: lane j&3 ends with gate j&3's dot.
        const bool lo2 = (j & 2) == 0;
        float u  = lo2 ? d2 : d0, v = lo2 ? d3 : d1;
        float ru = __shfl_xor(u, 2, 64), rv = __shfl_xor(v, 2, 64);
        float aa = (lo2 ? d0 : d2) + ru;
        float bb = (lo2 ? d1 : d3) + rv;
        const bool lo1 = (j & 1) == 0;
        float ws = lo1 ? bb : aa;
        float rw = __shfl_xor(ws, 1, 64);
        float s  = (lo1 ? aa : bb) + rw;

        s += isA ? xg_cur : addend_b;
        // One activation per lane: sigmoid (i,f,o) or tanh (g).
        float e   = __expf(mco * s);
        float act = fmaf(Bco, fast_rcp(1.f + e), Aco);

        // Allgather the 4 acts back across the quad (3 shuffles).
        float o1 = __shfl_xor(act, 1, 64);
        float ge = lo1 ? act : o1;         // even gate of this pair (i or g)
        float go = lo1 ? o1 : act;         // odd  gate (f or o)
        float pe = __shfl_xor(ge, 2, 64), po = __shfl_xor(go, 2, 64);
        float iact = lo2 ? ge : pe;
        float fact = lo2 ? go : po;
        float gact = lo2 ? pe : ge;
        float oact = lo2 ? po : go;

        const bool active = isA ? (k < TSZ) : (k >= 1);
        if (active) {
            c = fact * c + iact * gact;
            float hn = oact * tanh_f(c);
            if (j == 0) {
                if (isA) h0b[k & 1][q] = hn;              // h0(k)
                else     h1b[(k ^ 1) & 1][q] = hn;        // h1(k-1)
            }
        }
        xg_cur = xg_nxt;
        sync_lds();                        // lgkm-only: vmem stays in flight
    }

    // FC head on h1(T-1) = h1b[1] (wave 0 only).
    if (tid < HSZ) {
        float v = fmaxf(h1b[1][tid], 0.f) * fc_w[tid];
        #pragma unroll
        for (int off = 32; off > 0; off >>= 1) v += __shfl_down(v, off, 64);
        if (tid == 0) out[b] = sigmoid_f(v + fc_b[0]);
    }
}

extern "C" void kernel_launch(void* const* d_in, const int* in_sizes, int n_in,
                              void* d_out, int out_size, void* d_ws, size_t ws_size,
                              hipStream_t stream) {
    const int*   x     = (const int*)  d_in[0];
    const float* emb   = (const float*)d_in[1];
    const float* w_ih0 = (const float*)d_in[2];
    const float* w_hh0 = (const float*)d_in[3];
    const float* b_ih0 = (const float*)d_in[4];
    const float* b_hh0 = (const float*)d_in[5];
    const float* w_ih1 = (const float*)d_in[6];
    const float* w_hh1 = (const float*)d_in[7];
    const float* b_ih1 = (const float*)d_in[8];
    const float* b_hh1 = (const float*)d_in[9];
    const float* fc_w  = (const float*)d_in[10];
    const float* fc_b  = (const float*)d_in[11];
    float* out = (float*)d_out;

    // Workspace: permuted G table [V, 4H] fp32 = 51.2 MB.
    float* Gt = (float*)d_ws;

    build_table<<<dim3((VSZ + 31) / 32), dim3(256), 0, stream>>>(
        emb, w_ih0, b_ih0, b_hh0, Gt);
    lstm_fused<<<dim3(BSZ), dim3(768), 0, stream>>>(
        x, Gt, w_hh0, w_ih1, w_hh1, b_ih1, b_hh1, fc_w, fc_b, out);
}

// Round 9
// 526.803 us; speedup vs baseline: 1.0702x; 1.0198x over previous
//
#include <hip/hip_runtime.h>

// Problem constants (fixed by the reference setup_inputs).
#define VSZ 50000   // vocab
#define ESZ 100     // embedding dim
#define HSZ 64      // hidden
#define GSZ 256     // 4*H (gate width, PyTorch order i,f,g,o)
#define BSZ 256     // batch
#define TSZ 512     // seq len

typedef _Float16 halfv2 __attribute__((ext_vector_type(2)));

__device__ __forceinline__ float fast_rcp(float x) { return __builtin_amdgcn_rcpf(x); }
__device__ __forceinline__ float sigmoid_f(float x) { return fast_rcp(1.f + __expf(-x)); }
__device__ __forceinline__ float tanh_f(float x) {
    float e = __expf(2.f * x);
    return 1.f - 2.f * fast_rcp(e + 1.f);
}
__device__ __forceinline__ float fdot2f(halfv2 a, halfv2 b, float c) {
    return __builtin_amdgcn_fdot2(a, b, c, false);   // f16*f16 -> f32 acc
}
__device__ __forceinline__ halfv2 pk_lo(float4 f) {
    halfv2 r; r[0] = (_Float16)f.x; r[1] = (_Float16)f.y; return r;
}
__device__ __forceinline__ halfv2 pk_hi(float4 f) {
    halfv2 r; r[0] = (_Float16)f.z; r[1] = (_Float16)f.w; return r;
}

// ---------------------------------------------------------------------------
// Kernel A: G[v, col] = sum_e emb[v,e]*w_ih0[row,e] + b_ih0[row] + b_hh0[row],
// PERMUTED col = 4*(row%64) + row/64 so the recurrent kernel's lane (q,j)
// reads its gate scalar at col 4q+j. (r5 s_load form -- measured fastest.)
// Unchanged from r8.
// ---------------------------------------------------------------------------
__global__ __launch_bounds__(256) void build_table(
    const float* __restrict__ emb, const float* __restrict__ w_ih0,
    const float* __restrict__ b_ih0, const float* __restrict__ b_hh0,
    float* __restrict__ Gt)
{
    const int g = threadIdx.x;            // PyTorch gate-row index 0..255
    const int row0 = blockIdx.x * 32;
    const int col = ((g & 63) << 2) + (g >> 6);   // permuted column

    float w[ESZ];
    #pragma unroll
    for (int e = 0; e < ESZ; e += 4) {
        float4 v = *(const float4*)(w_ih0 + g * ESZ + e);
        w[e] = v.x; w[e + 1] = v.y; w[e + 2] = v.z; w[e + 3] = v.w;
    }
    const float bias = b_ih0[g] + b_hh0[g];

    #pragma unroll 1
    for (int r = row0; r < row0 + 32 && r < VSZ; r += 4) {
        const int off0 = __builtin_amdgcn_readfirstlane(r * ESZ);
        const float* e0 = emb + off0;
        const float* e1 = e0 + ESZ;
        const float* e2 = e0 + 2 * ESZ;
        const float* e3 = e0 + 3 * ESZ;
        float a0 = bias, a1 = 0.f, a2 = 0.f, a3 = 0.f;
        float b0 = bias, b1 = 0.f, b2 = 0.f, b3 = 0.f;
        float c0 = bias, c1 = 0.f, c2 = 0.f, c3 = 0.f;
        float d0 = bias, d1 = 0.f, d2 = 0.f, d3 = 0.f;
        #pragma unroll
        for (int e = 0; e < ESZ; e += 4) {
            a0 += e0[e    ] * w[e    ]; a1 += e0[e + 1] * w[e + 1];
            a2 += e0[e + 2] * w[e + 2]; a3 += e0[e + 3] * w[e + 3];
            b0 += e1[e    ] * w[e    ]; b1 += e1[e + 1] * w[e + 1];
            b2 += e1[e + 2] * w[e + 2]; b3 += e1[e + 3] * w[e + 3];
            c0 += e2[e    ] * w[e    ]; c1 += e2[e + 1] * w[e + 1];
            c2 += e2[e + 2] * w[e + 2]; c3 += e2[e + 3] * w[e + 3];
            d0 += e3[e    ] * w[e    ]; d1 += e3[e + 1] * w[e + 1];
            d2 += e3[e + 2] * w[e + 2]; d3 += e3[e + 3] * w[e + 3];
        }
        Gt[(size_t)r       * GSZ + col] = (a0 + a1) + (a2 + a3);
        Gt[(size_t)(r + 1) * GSZ + col] = (b0 + b1) + (b2 + b3);
        Gt[(size_t)(r + 2) * GSZ + col] = (c0 + c1) + (c2 + c3);
        Gt[(size_t)(r + 3) * GSZ + col] = (d0 + d1) + (d2 + d3);
    }
}

// ---------------------------------------------------------------------------
// Kernel B: fused 2-layer LSTM + FC head, 1 block (768 thr) per batch row.
//
// r9 change: fp16-packed weights + v_dot2_f32_f16.
// r4-r8 proved the allocator will NOT keep 64 fp32 weight floats resident
// (VGPR pinned at 52 under every attribute combo; 196KB/CU/step scratch
// restream through L2 ~= the whole 2000cy step time). Instead of raising
// the ceiling, shrink the need: 64 weights -> 32 VGPRs as _Float16 pairs,
// consumed by fdot2 (f16xf16 products, FP32 ACCUMULATE, 2 MACs/inst).
// h is published to LDS as fp16 (broadcast b128 reads); c-state, gates,
// activations, Gt, biases, FC all remain fp32. Only rounding of w and h
// (rel 5e-4) enters: expected absmax ~1e-3.
//
// Decomposition unchanged: A (tid<256) layer 0, q=tid>>2, j=tid&3;
// B (tid>=256) layer 1, q=lt>>3, j=lt&7, H = h0-slice ++ h1-slice.
// Per step: 32 fdot2 -> quad reduce-scatter -> ONE activation/lane ->
// 3-shuffle allgather -> replicated c,h update -> lane j==0 publishes fp16 h.
// ONE lgkm-only barrier per step (Gt prefetch stays in flight).
// ---------------------------------------------------------------------------
__device__ __forceinline__ void sync_lds() {
    asm volatile("s_waitcnt lgkmcnt(0)\n\ts_barrier" ::: "memory");
}

#define LD4(ptr, off) (*(const float4*)((ptr) + (off)))
#define PIN2(v) asm volatile("" : "+v"(v))
#define LOADG(T0,T1,T2,T3,T4,T5,T6,T7, off) {                         \
    float4 f0 = LD4(pw1, off), f1 = LD4(pw1, (off) + 4);              \
    float4 f2 = LD4(pw2, off), f3 = LD4(pw2, (off) + 4);              \
    T0 = pk_lo(f0); T1 = pk_hi(f0); T2 = pk_lo(f1); T3 = pk_hi(f1);   \
    T4 = pk_lo(f2); T5 = pk_hi(f2); T6 = pk_lo(f3); T7 = pk_hi(f3); }
#define DOT4(d, A0,A1,A2,A3)                                          \
    d = fdot2f(A0, H0, d); d = fdot2f(A1, H1, d);                     \
    d = fdot2f(A2, H2, d); d = fdot2f(A3, H3, d);

__global__
__attribute__((amdgpu_flat_work_group_size(768, 768),
               amdgpu_waves_per_eu(2, 3)))
void lstm_fused(
    const int* __restrict__ x, const float* __restrict__ Gt,
    const float* __restrict__ w_hh0,
    const float* __restrict__ w_ih1, const float* __restrict__ w_hh1,
    const float* __restrict__ b_ih1, const float* __restrict__ b_hh1,
    const float* __restrict__ fc_w, const float* __restrict__ fc_b,
    float* __restrict__ out)
{
    const int tid = threadIdx.x;
    const int b   = blockIdx.x;
    const bool isA = tid < 256;
    const int lt  = isA ? tid : (tid - 256);
    const int q   = isA ? (lt >> 2) : (lt >> 3);
    const int j   = isA ? (lt & 3) : (lt & 7);
    const int gt  = j & 3;                 // gate this lane owns post-reduce

    // h state, fp16: rows 0,1 = h0 (double-buffered), rows 2,3 = h1.
    __shared__ __align__(16) _Float16 hst[4][HSZ];
    __shared__ int xtok[TSZ];

    // Weight slice pointers (row of gate g = g*64+q -> +g*4096 elements).
    const float* pw1 = isA ? (w_hh0 + q * HSZ + 16 * j)
                           : (w_ih1 + q * HSZ + 8 * j);
    const float* pw2 = isA ? (w_hh0 + q * HSZ + 16 * j + 8)
                           : (w_hh1 + q * HSZ + 8 * j);

    halfv2 T00,T01,T02,T03,T04,T05,T06,T07;
    halfv2 T10,T11,T12,T13,T14,T15,T16,T17;
    halfv2 T20,T21,T22,T23,T24,T25,T26,T27;
    halfv2 T30,T31,T32,T33,T34,T35,T36,T37;
    LOADG(T00,T01,T02,T03,T04,T05,T06,T07, 0);
    LOADG(T10,T11,T12,T13,T14,T15,T16,T17, 4096);
    LOADG(T20,T21,T22,T23,T24,T25,T26,T27, 8192);
    LOADG(T30,T31,T32,T33,T34,T35,T36,T37, 12288);
    // One-time volatile pins (32 VGPRs total -- fits the allocator's budget).
    PIN2(T00);PIN2(T01);PIN2(T02);PIN2(T03);PIN2(T04);PIN2(T05);PIN2(T06);PIN2(T07);
    PIN2(T10);PIN2(T11);PIN2(T12);PIN2(T13);PIN2(T14);PIN2(T15);PIN2(T16);PIN2(T17);
    PIN2(T20);PIN2(T21);PIN2(T22);PIN2(T23);PIN2(T24);PIN2(T25);PIN2(T26);PIN2(T27);
    PIN2(T30);PIN2(T31);PIN2(T32);PIN2(T33);PIN2(T34);PIN2(T35);PIN2(T36);PIN2(T37);

    float addend_b = 0.f;                  // B: bias of its gate (invariant)
    if (!isA) addend_b = b_ih1[gt * HSZ + q] + b_hh1[gt * HSZ + q];
    const float mco = (gt == 2) ?  2.f : -1.f;   // unified activation consts
    const float Aco = (gt == 2) ?  1.f :  0.f;
    const float Bco = (gt == 2) ? -2.f :  1.f;

    if (tid < 256) ((unsigned short*)hst)[tid] = 0;      // zero all 4 rows
    if (tid < TSZ) xtok[tid] = x[b * TSZ + tid];
    __syncthreads();

    float c = 0.f;
    float xg_cur = 0.f;
    if (isA) xg_cur = Gt[(size_t)xtok[0] * GSZ + 4 * q + j];

    #pragma unroll 1
    for (int k = 0; k <= TSZ; ++k) {
        // A: prefetch next token's gate scalar (survives the lgkm barrier).
        float xg_nxt = 0.f;
        if (isA && k + 1 < TSZ)
            xg_nxt = Gt[(size_t)xtok[k + 1] * GSZ + 4 * q + j];

        const int rb = (k ^ 1) & 1;                       // h0(k-1) row
        const _Float16* hr0 = hst[rb];
        // First operand half: A = h0[16j..16j+8), B = h0[8j..8j+8).
        const halfv2* pA = isA ? (const halfv2*)(hr0 + 16 * j)
                               : (const halfv2*)(hr0 + 8 * j);
        halfv2 H0 = pA[0], H1 = pA[1], H2 = pA[2], H3 = pA[3];
        float d0 = 0.f, d1 = 0.f, d2 = 0.f, d3 = 0.f;
        DOT4(d0, T00,T01,T02,T03);
        DOT4(d1, T10,T11,T12,T13);
        DOT4(d2, T20,T21,T22,T23);
        DOT4(d3, T30,T31,T32,T33);
        // Second half: A = h0[16j+8..16j+16), B = h1(k-2)[8j..8j+8).
        const halfv2* pB = isA ? (pA + 4)
                               : (const halfv2*)(hst[2 + (k & 1)] + 8 * j);
        H0 = pB[0]; H1 = pB[1]; H2 = pB[2]; H3 = pB[3];
        DOT4(d0, T04,T05,T06,T07);
        DOT4(d1, T14,T15,T16,T17);
        DOT4(d2, T24,T25,T26,T27);
        DOT4(d3, T34,T35,T36,T37);

        if (!isA) {                        // fold the two octet halves
            d0 += __shfl_xor(d0, 4, 64); d1 += __shfl_xor(d1, 4, 64);
            d2 += __shfl_xor(d2, 4, 64); d3 += __shfl_xor(d3, 4, 64);
        }
        // Reduce-scatter within quad: lane j&3 ends with gate j&3's dot.
        const bool lo2 = (j & 2) == 0;
        float u  = lo2 ? d2 : d0, v = lo2 ? d3 : d1;
        float ru = __shfl_xor(u, 2, 64), rv = __shfl_xor(v, 2, 64);
        float aa = (lo2 ? d0 : d2) + ru;
        float bb = (lo2 ? d1 : d3) + rv;
        const bool lo1 = (j & 1) == 0;
        float ws = lo1 ? bb : aa;
        float rw = __shfl_xor(ws, 1, 64);
        float s  = (lo1 ? aa : bb) + rw;

        s += isA ? xg_cur : addend_b;
        // One activation per lane: sigmoid (i,f,o) or tanh (g).
        float e   = __expf(mco * s);
        float act = fmaf(Bco, fast_rcp(1.f + e), Aco);

        // Allgather the 4 acts back across the quad (3 shuffles).
        float o1 = __shfl_xor(act, 1, 64);
        float ge = lo1 ? act : o1;         // even gate of this pair (i or g)
        float go = lo1 ? o1 : act;         // odd  gate (f or o)
        float pe = __shfl_xor(ge, 2, 64), po = __shfl_xor(go, 2, 64);
        float iact = lo2 ? ge : pe;
        float fact = lo2 ? go : po;
        float gact = lo2 ? pe : ge;
        float oact = lo2 ? po : go;

        const bool active = isA ? (k < TSZ) : (k >= 1);
        if (active) {
            c = fact * c + iact * gact;
            float hn = oact * tanh_f(c);
            if (j == 0) {
                if (isA) hst[k & 1][q] = (_Float16)hn;          // h0(k)
                else     hst[2 + ((k ^ 1) & 1)][q] = (_Float16)hn; // h1(k-1)
            }
        }
        xg_cur = xg_nxt;
        sync_lds();                        // lgkm-only: vmem stays in flight
    }

    // FC head on h1(T-1) = hst[3] (wave 0 only).
    if (tid < HSZ) {
        float v = fmaxf((float)hst[3][tid], 0.f) * fc_w[tid];
        #pragma unroll
        for (int off = 32; off > 0; off >>= 1) v += __shfl_down(v, off, 64);
        if (tid == 0) out[b] = sigmoid_f(v + fc_b[0]);
    }
}

extern "C" void kernel_launch(void* const* d_in, const int* in_sizes, int n_in,
                              void* d_out, int out_size, void* d_ws, size_t ws_size,
                              hipStream_t stream) {
    const int*   x     = (const int*)  d_in[0];
    const float* emb   = (const float*)d_in[1];
    const float* w_ih0 = (const float*)d_in[2];
    const float* w_hh0 = (const float*)d_in[3];
    const float* b_ih0 = (const float*)d_in[4];
    const float* b_hh0 = (const float*)d_in[5];
    const float* w_ih1 = (const float*)d_in[6];
    const float* w_hh1 = (const float*)d_in[7];
    const float* b_ih1 = (const float*)d_in[8];
    const float* b_hh1 = (const float*)d_in[9];
    const float* fc_w  = (const float*)d_in[10];
    const float* fc_b  = (const float*)d_in[11];
    float* out = (float*)d_out;

    // Workspace: permuted G table [V, 4H] fp32 = 51.2 MB.
    float* Gt = (float*)d_ws;

    build_table<<<dim3((VSZ + 31) / 32), dim3(256), 0, stream>>>(
        emb, w_ih0, b_ih0, b_hh0, Gt);
    lstm_fused<<<dim3(BSZ), dim3(768), 0, stream>>>(
        x, Gt, w_hh0, w_ih1, w_hh1, b_ih1, b_hh1, fc_w, fc_b, out);
}